// Round 1
// baseline (153.322 us; speedup 1.0000x reference)
//
#include <hip/hip_runtime.h>
#include <math.h>

// QueryDynamicAttention: B=16, N=1024, D=768, MU=768, R=16, DR=48
// out = (x * sigmoid(channel_att)) * sigmoid(spatial)
//   channel_att = W2 @ (relu(W1@avg+b1) + relu(W1@max+b1)) + 2*b2   (linear-layer merge)
//   spatial[b,n] = dot(x_gated[b,n,:], Ws[b,:]) + bs[b]
// All per-sample weights come from mu via hypernet GEMMs (M=16,K=768) — HBM-bound.

#define B_  16
#define N_  1024
#define D_  768
#define MU_ 768
#define DR_ 48

// ws layout (float offsets); total ~8.07 MB (assumes ws_size >= 8.1 MB)
#define OFF_MUT   0            // mu_t [768][16]
#define OFF_PSUM  12288        // psum [32][16][768]
#define OFF_PMAX  405504       // pmax [32][16][768]
#define OFF_W1    798720       // W1   [16][36864]  (= [16][48][768])
#define OFF_W2    1388544      // W2   [16][36864]  (= [16][768][48])
#define OFF_WSW   1978368      // Ws   [16][768]
#define OFF_B1    1990656      // b1   [16][48]
#define OFF_B2    1991424      // b2   [16][768]
#define OFF_BS    2003712      // bs   [16]
#define OFF_G     2003728      // g    [16][48]
#define OFF_CG    2004496      // cg   [16][768]

// ---------------------------------------------------------------------------
// k_pool: avg/max pooling partials over N (32 chunks of 32 tokens) + mu transpose
// grid 513 x 192
__global__ __launch_bounds__(192) void k_pool(
    const float* __restrict__ x, const float* __restrict__ mu,
    float* __restrict__ ws)
{
    float* mu_t = ws + OFF_MUT;
    float* psum = ws + OFF_PSUM;
    float* pmax = ws + OFF_PMAX;
    int blk = blockIdx.x;
    if (blk == 512) {  // mu transpose: mu_t[m][b] = mu[b][m]
        for (int e = threadIdx.x; e < MU_ * B_; e += 192) {
            int m = e >> 4, b = e & 15;
            mu_t[e] = mu[b * MU_ + m];
        }
        return;
    }
    int b = blk >> 5, c = blk & 31;
    int d4 = threadIdx.x << 2;                       // 192 threads * 4 = 768 cols
    const float* xp = x + ((size_t)(b * N_ + c * 32)) * D_ + d4;
    float s0 = 0.f, s1 = 0.f, s2 = 0.f, s3 = 0.f;
    float m0 = -3.4e38f, m1 = -3.4e38f, m2 = -3.4e38f, m3 = -3.4e38f;
    for (int n = 0; n < 32; ++n) {
        float4 v = *(const float4*)(xp + (size_t)n * D_);
        s0 += v.x; s1 += v.y; s2 += v.z; s3 += v.w;
        m0 = fmaxf(m0, v.x); m1 = fmaxf(m1, v.y);
        m2 = fmaxf(m2, v.z); m3 = fmaxf(m3, v.w);
    }
    size_t o = ((size_t)(c * B_ + b)) * D_ + d4;
    float4 sv = { s0, s1, s2, s3 }; *(float4*)(psum + o) = sv;
    float4 mv = { m0, m1, m2, m3 }; *(float4*)(pmax + o) = mv;
}

// ---------------------------------------------------------------------------
// k_hyper: out[b][j] = sum_m mu[b][m] * M[m][j] + bias[j], for 6 matrices.
// One wave per 64-column tile; acc[16] per lane; mu_t reads are wave-uniform
// (should lower to s_load). 1178 blocks x 64 threads.
__global__ __launch_bounds__(64) void k_hyper(
    const float* __restrict__ Wg1, const float* __restrict__ bg1,
    const float* __restrict__ Wg2, const float* __restrict__ bg2,
    const float* __restrict__ Wgs, const float* __restrict__ bgs,
    const float* __restrict__ Bg1, const float* __restrict__ bb1,
    const float* __restrict__ Bg2, const float* __restrict__ bb2,
    const float* __restrict__ Bgs, const float* __restrict__ bbs,
    float* __restrict__ ws)
{
    const float* mu_t = ws + OFF_MUT;
    int t = blockIdx.x;
    const float* mat; const float* bias; float* out; int ncols; int tile;
    if (t < 576)        { mat = Wg1; bias = bg1; out = ws + OFF_W1;  ncols = 36864; tile = t; }
    else if (t < 1152)  { mat = Wg2; bias = bg2; out = ws + OFF_W2;  ncols = 36864; tile = t - 576; }
    else if (t < 1164)  { mat = Wgs; bias = bgs; out = ws + OFF_WSW; ncols = 768;   tile = t - 1152; }
    else if (t == 1164) { mat = Bg1; bias = bb1; out = ws + OFF_B1;  ncols = 48;    tile = 0; }
    else if (t < 1177)  { mat = Bg2; bias = bb2; out = ws + OFF_B2;  ncols = 768;   tile = t - 1165; }
    else                { mat = Bgs; bias = bbs; out = ws + OFF_BS;  ncols = 1;     tile = 0; }

    int j = (tile << 6) + threadIdx.x;
    bool valid = j < ncols;
    int jc = valid ? j : 0;                 // clamp: OOB lanes read col 0, never store
    const float* p = mat + jc;

    float acc[16];
    #pragma unroll
    for (int b = 0; b < 16; ++b) acc[b] = 0.f;

    #pragma unroll 8
    for (int m = 0; m < MU_; ++m) {
        float w = *p; p += ncols;
        const float* mr = mu_t + (m << 4);  // wave-uniform address
        #pragma unroll
        for (int b = 0; b < 16; ++b) acc[b] = fmaf(mr[b], w, acc[b]);
    }

    if (valid) {
        float bv = bias[j];
        #pragma unroll
        for (int b = 0; b < 16; ++b) out[(size_t)b * ncols + j] = acc[b] + bv;
    }
}

// ---------------------------------------------------------------------------
// k_c1: finish pooling, h1 = W1@{avg,max}+b1, g = relu(ha)+relu(hm). grid 16 x 512.
__global__ __launch_bounds__(512) void k_c1(float* __restrict__ ws)
{
    const float* psum = ws + OFF_PSUM;
    const float* pmax = ws + OFF_PMAX;
    const float* W1   = ws + OFF_W1;
    const float* b1w  = ws + OFF_B1;
    float* g          = ws + OFF_G;
    __shared__ float avgL[768], maxL[768], b1L[48];
    int b = blockIdx.x, tid = threadIdx.x;
    for (int d = tid; d < D_; d += 512) {
        float s = 0.f, mx = -3.4e38f;
        for (int c = 0; c < 32; ++c) {
            size_t idx = ((size_t)(c * B_ + b)) * D_ + d;
            s += psum[idx];
            mx = fmaxf(mx, pmax[idx]);
        }
        avgL[d] = s * (1.f / 1024.f);
        maxL[d] = mx;
    }
    if (tid < 48) b1L[tid] = b1w[b * 48 + tid];
    __syncthreads();
    int wv = tid >> 6, ln = tid & 63;
    for (int o = wv; o < 48; o += 8) {
        const float* w1 = W1 + (size_t)b * 36864 + o * 768;
        float pa = 0.f, pm = 0.f;
        for (int i = ln; i < 768; i += 64) {
            float w = w1[i];
            pa += w * avgL[i];
            pm += w * maxL[i];
        }
        #pragma unroll
        for (int k = 32; k; k >>= 1) {
            pa += __shfl_xor(pa, k, 64);
            pm += __shfl_xor(pm, k, 64);
        }
        if (ln == 0) {
            float bb = b1L[o];
            g[b * 48 + o] = fmaxf(pa + bb, 0.f) + fmaxf(pm + bb, 0.f);
        }
    }
}

// ---------------------------------------------------------------------------
// k_c2: channel_att = W2@g + 2*b2; cg = sigmoid. grid 96 x 128.
__global__ __launch_bounds__(128) void k_c2(float* __restrict__ ws)
{
    const float* W2  = ws + OFF_W2;
    const float* b2w = ws + OFF_B2;
    const float* g   = ws + OFF_G;
    float* cg        = ws + OFF_CG;
    __shared__ float gL[48];
    int b = blockIdx.x / 6, ch = blockIdx.x % 6;
    if (threadIdx.x < 48) gL[threadIdx.x] = g[b * 48 + threadIdx.x];
    __syncthreads();
    int d = (ch << 7) + threadIdx.x;
    const float* row = W2 + (size_t)b * 36864 + d * 48;
    float att = 0.f;
    #pragma unroll
    for (int o = 0; o < 48; o += 4) {
        float4 w4 = *(const float4*)(row + o);
        att += w4.x * gL[o] + w4.y * gL[o + 1] + w4.z * gL[o + 2] + w4.w * gL[o + 3];
    }
    att += 2.f * b2w[b * D_ + d];
    cg[b * D_ + d] = 1.f / (1.f + expf(-att));
}

// ---------------------------------------------------------------------------
// k_final: one wave per token: xg = x*cg; s = dot(xg, Ws)+bs; out = xg*sigmoid(s).
// grid 4096 x 256 (4 waves/block).
__global__ __launch_bounds__(256) void k_final(
    const float* __restrict__ x, const float* __restrict__ ws,
    float* __restrict__ out)
{
    const float* cg  = ws + OFF_CG;
    const float* wsw = ws + OFF_WSW;
    const float* bs  = ws + OFF_BS;
    int wv = threadIdx.x >> 6, ln = threadIdx.x & 63;
    int tok = (blockIdx.x << 2) + wv;
    int b = tok >> 10;
    const float* xp = x + (size_t)tok * D_;
    const float* cp = cg + b * D_;
    const float* wp = wsw + b * D_;
    float xg[12];
    float part = 0.f;
    #pragma unroll
    for (int q = 0; q < 3; ++q) {
        int d = (q << 8) + (ln << 2);
        float4 xv = *(const float4*)(xp + d);
        float4 cv = *(const float4*)(cp + d);
        float4 w4 = *(const float4*)(wp + d);
        float g0 = xv.x * cv.x, g1 = xv.y * cv.y;
        float g2 = xv.z * cv.z, g3 = xv.w * cv.w;
        part += g0 * w4.x + g1 * w4.y + g2 * w4.z + g3 * w4.w;
        xg[q * 4 + 0] = g0; xg[q * 4 + 1] = g1;
        xg[q * 4 + 2] = g2; xg[q * 4 + 3] = g3;
    }
    #pragma unroll
    for (int k = 32; k; k >>= 1) part += __shfl_xor(part, k, 64);
    float s = part + bs[b];
    float sig = 1.f / (1.f + expf(-s));
    #pragma unroll
    for (int q = 0; q < 3; ++q) {
        int d = (q << 8) + (ln << 2);
        float4 o4 = { xg[q * 4 + 0] * sig, xg[q * 4 + 1] * sig,
                      xg[q * 4 + 2] * sig, xg[q * 4 + 3] * sig };
        *(float4*)(out + (size_t)tok * D_ + d) = o4;
    }
}

// ---------------------------------------------------------------------------
extern "C" void kernel_launch(void* const* d_in, const int* in_sizes, int n_in,
                              void* d_out, int out_size, void* d_ws, size_t ws_size,
                              hipStream_t stream)
{
    const float* x   = (const float*)d_in[0];
    const float* mu  = (const float*)d_in[1];
    const float* Wg1 = (const float*)d_in[2];
    const float* bg1 = (const float*)d_in[3];
    const float* Bg1 = (const float*)d_in[4];
    const float* bb1 = (const float*)d_in[5];
    const float* Wg2 = (const float*)d_in[6];
    const float* bg2 = (const float*)d_in[7];
    const float* Bg2 = (const float*)d_in[8];
    const float* bb2 = (const float*)d_in[9];
    const float* Wgs = (const float*)d_in[10];
    const float* bgs = (const float*)d_in[11];
    const float* Bgs = (const float*)d_in[12];
    const float* bbs = (const float*)d_in[13];
    float* ws  = (float*)d_ws;
    float* out = (float*)d_out;

    hipLaunchKernelGGL(k_pool,  dim3(513),  dim3(192), 0, stream, x, mu, ws);
    hipLaunchKernelGGL(k_hyper, dim3(1178), dim3(64),  0, stream,
                       Wg1, bg1, Wg2, bg2, Wgs, bgs, Bg1, bb1, Bg2, bb2, Bgs, bbs, ws);
    hipLaunchKernelGGL(k_c1,    dim3(16),   dim3(512), 0, stream, ws);
    hipLaunchKernelGGL(k_c2,    dim3(96),   dim3(128), 0, stream, ws);
    hipLaunchKernelGGL(k_final, dim3(4096), dim3(256), 0, stream, x, ws, out);
}